// Round 2
// baseline (512.352 us; speedup 1.0000x reference)
//
#include <hip/hip_runtime.h>
#include <hip/hip_bf16.h>

#define HDIM 128

typedef short bf16x8 __attribute__((ext_vector_type(8)));
typedef unsigned short u16x8 __attribute__((ext_vector_type(8)));
typedef float f32x4 __attribute__((ext_vector_type(4)));

__device__ __forceinline__ short f2bf(float f) {
    __hip_bfloat16 h = __float2bfloat16(f);
    union { __hip_bfloat16 h; short s; } c; c.h = h; return c.s;
}
__device__ __forceinline__ float bf2f(unsigned short h) {
    union { unsigned u; float f; } c; c.u = ((unsigned)h) << 16; return c.f;
}
__device__ __forceinline__ bf16x8 pack8(float4 a, float4 b) {
    bf16x8 r;
    r[0] = f2bf(a.x); r[1] = f2bf(a.y); r[2] = f2bf(a.z); r[3] = f2bf(a.w);
    r[4] = f2bf(b.x); r[5] = f2bf(b.y); r[6] = f2bf(b.z); r[7] = f2bf(b.w);
    return r;
}

// ---- weight staging into MFMA B-fragment order (512-thread versions) ----
// Fragment (nt,kt): lane l holds B[k = kt*32 + (l>>4)*8 + i][n = nt*16 + (l&15)],
// stored at wfrag[((nt*4+kt)*64 + l)*8 + i] (bf16).
//
// stage_T: B[k][n] = W[n][k]  (for h = z @ W^T)
__device__ __forceinline__ void stage_T(const float* __restrict__ W, short* wfrag, int t) {
#pragma unroll
    for (int s = 0; s < 4; ++s) {
        int S = t + (s << 9);            // 0..2047
        int f = S >> 6, sl = S & 63;     // frag id, lane slot
        int n  = ((f >> 2) << 4) + (sl & 15);
        int k0 = ((f & 3) << 5) + ((sl >> 4) << 3);
        const float* p = W + n * HDIM + k0;
        float4 a = *(const float4*)p;
        float4 b = *(const float4*)(p + 4);
        *(bf16x8*)&wfrag[S << 3] = pack8(a, b);
    }
}
// stage_D: B[k][n] = W[k][n]  (for g1 = h1 @ wb)
__device__ __forceinline__ void stage_D(const float* __restrict__ W, short* wfrag, int t) {
#pragma unroll
    for (int s = 0; s < 4; ++s) {
        int S = t + (s << 9);
        int k  = S >> 4;
        int n0 = (S & 15) << 3;
        const float* p = W + k * HDIM + n0;
        float4 a = *(const float4*)p;
        float4 b = *(const float4*)(p + 4);
        float vals[8] = {a.x, a.y, a.z, a.w, b.x, b.y, b.z, b.w};
        int kt = k >> 5, kg = (k >> 3) & 3, i = k & 7;
        int nt = n0 >> 4;
        int fbase = ((nt << 2) + kt) << 6;
#pragma unroll
        for (int j = 0; j < 8; ++j) {
            int lanee = (kg << 4) + ((n0 + j) & 15);
            wfrag[((fbase + lanee) << 3) + i] = f2bf(vals[j]);
        }
    }
}

__device__ __forceinline__ void run_gemm8(const short* wfrag, const bf16x8* a, f32x4* acc, int lane) {
#pragma unroll
    for (int kt = 0; kt < 4; ++kt) {
#pragma unroll
        for (int nt = 0; nt < 8; ++nt) {
            bf16x8 b = *(const bf16x8*)&wfrag[((((nt << 2) + kt) << 6) + lane) << 3];
            acc[nt] = __builtin_amdgcn_mfma_f32_16x16x32_bf16(a[kt], b, acc[nt], 0, 0, 0);
        }
    }
}

// ---- phase 1 (persistent): per-node h1=relu(z@w1^T+b1); g1=h1@wb; h2=relu(z@w2^T+b2)
__global__ __launch_bounds__(512, 2)
void node_phase(const float* __restrict__ z,
                const float* __restrict__ w1, const float* __restrict__ b1,
                const float* __restrict__ w2, const float* __restrict__ b2,
                const float* __restrict__ wb,
                unsigned short* __restrict__ g1, unsigned short* __restrict__ h2o,
                int N)
{
    __shared__ short wf1[16384];            // 32 KB each
    __shared__ short wf2[16384];
    __shared__ short wfb[16384];
    __shared__ short h1buf[8 * 16 * HDIM];  // 32 KB, per-wave 16x128 swizzled

    const int t = threadIdx.x;
    const int lane = t & 63, wid = t >> 6;
    const int l15 = lane & 15, kgrp = lane >> 4;

    // stage all weights ONCE per block
    stage_T(w1, wf1, t);
    stage_T(w2, wf2, t);
    stage_D(wb, wfb, t);

    float bias1[8], bias2[8];
#pragma unroll
    for (int nt = 0; nt < 8; ++nt) {
        bias1[nt] = b1[nt * 16 + l15];
        bias2[nt] = b2[nt * 16 + l15];
    }
    __syncthreads();   // only barrier in the kernel

    const int ntiles = (N + 127) >> 7;
    const int wbase = wid * (16 * HDIM);

    float4 cur[8];
    int tile = blockIdx.x;
    if (tile < ntiles) {
        int m = tile * 128 + wid * 16 + l15;
        int mc = m < N ? m : N - 1;
        const float4* zr = (const float4*)(z + (size_t)mc * HDIM);
#pragma unroll
        for (int kt = 0; kt < 4; ++kt) {
            cur[2 * kt]     = zr[kt * 8 + kgrp * 2];
            cur[2 * kt + 1] = zr[kt * 8 + kgrp * 2 + 1];
        }
    }

    for (; tile < ntiles; tile += gridDim.x) {
        // ---- prefetch next tile's z rows (latency hides under 3 GEMMs) ----
        float4 nxt[8];
        int tnext = tile + gridDim.x;
        if (tnext < ntiles) {
            int m = tnext * 128 + wid * 16 + l15;
            int mc = m < N ? m : N - 1;
            const float4* zr = (const float4*)(z + (size_t)mc * HDIM);
#pragma unroll
            for (int kt = 0; kt < 4; ++kt) {
                nxt[2 * kt]     = zr[kt * 8 + kgrp * 2];
                nxt[2 * kt + 1] = zr[kt * 8 + kgrp * 2 + 1];
            }
        }

        bf16x8 za[4];
#pragma unroll
        for (int kt = 0; kt < 4; ++kt) za[kt] = pack8(cur[2 * kt], cur[2 * kt + 1]);

        const int mbase = tile * 128 + wid * 16;

        // ---- GEMM1: h1 = relu(z @ w1^T + b1) ----
        f32x4 acc[8];
#pragma unroll
        for (int nt = 0; nt < 8; ++nt) {
            float bv = bias1[nt];
            acc[nt] = (f32x4){bv, bv, bv, bv};
        }
        run_gemm8(wf1, za, acc, lane);

        // relu -> per-wave swizzled LDS tile (bf16)
#pragma unroll
        for (int nt = 0; nt < 8; ++nt) {
#pragma unroll
            for (int r = 0; r < 4; ++r) {
                float v = acc[nt][r]; v = v > 0.f ? v : 0.f;
                int row = kgrp * 4 + r;
                int col = nt * 16 + l15;
                h1buf[wbase + row * HDIM + (col ^ ((row & 7) << 3))] = f2bf(v);
            }
        }

        // ---- GEMM3: h2 = relu(z @ w2^T + b2)  (h1buf writes settle under this) ----
        f32x4 acc2[8];
#pragma unroll
        for (int nt = 0; nt < 8; ++nt) {
            float bv = bias2[nt];
            acc2[nt] = (f32x4){bv, bv, bv, bv};
        }
        run_gemm8(wf2, za, acc2, lane);

        // read h1 back as A fragments (same wave -> ordered by lgkmcnt)
        bf16x8 a2[4];
        {
            int row = l15;
#pragma unroll
            for (int kt = 0; kt < 4; ++kt) {
                int col = kt * 32 + kgrp * 8;
                a2[kt] = *(const bf16x8*)&h1buf[wbase + row * HDIM + (col ^ ((row & 7) << 3))];
            }
        }

        // store h2
#pragma unroll
        for (int nt = 0; nt < 8; ++nt) {
#pragma unroll
            for (int r = 0; r < 4; ++r) {
                float v = acc2[nt][r]; v = v > 0.f ? v : 0.f;
                int m = mbase + kgrp * 4 + r;
                if (m < N) h2o[(size_t)m * HDIM + nt * 16 + l15] = (unsigned short)f2bf(v);
            }
        }

        // ---- GEMM2: g1 = h1 @ wb ----
        f32x4 accg[8];
#pragma unroll
        for (int nt = 0; nt < 8; ++nt) accg[nt] = (f32x4){0.f, 0.f, 0.f, 0.f};
        run_gemm8(wfb, a2, accg, lane);
#pragma unroll
        for (int nt = 0; nt < 8; ++nt) {
#pragma unroll
            for (int r = 0; r < 4; ++r) {
                int m = mbase + kgrp * 4 + r;
                if (m < N) g1[(size_t)m * HDIM + nt * 16 + l15] = (unsigned short)f2bf(accg[nt][r]);
            }
        }

        // rotate double buffer
#pragma unroll
        for (int q = 0; q < 8; ++q) cur[q] = nxt[q];
    }
}

// ---- index dtype detection: int64 arcs have zero high words -------------
__global__ void detect_idx64(const int* __restrict__ arcs, int* __restrict__ flag)
{
    if (threadIdx.x == 0) {
        int is64 = 1;
        for (int j = 0; j < 64; ++j)
            if (arcs[2 * j + 1] != 0) { is64 = 0; break; }
        *flag = is64;
    }
}

// ---- phase 2: score[e] = dot(g1[u], h2[v]) + bb -------------------------
__global__ __launch_bounds__(256, 8)
void edge_phase(const unsigned short* __restrict__ g1,
                const unsigned short* __restrict__ h2,
                const void* __restrict__ arcs,
                const int* __restrict__ flag,
                const float* __restrict__ bb,
                float* __restrict__ out, int E)
{
    const int t = threadIdx.x;
    const int sub = t & 15;
    const int e = blockIdx.x * 16 + (t >> 4);
    const int ec = e < E ? e : (E - 1);

    long long u, v;
    if (*flag) {
        const long long* a = (const long long*)arcs;
        u = a[2 * (size_t)ec]; v = a[2 * (size_t)ec + 1];
    } else {
        const int* a = (const int*)arcs;
        u = a[2 * (size_t)ec]; v = a[2 * (size_t)ec + 1];
    }

    u16x8 av = *(const u16x8*)(g1 + (size_t)u * HDIM + sub * 8);
    u16x8 bv = *(const u16x8*)(h2 + (size_t)v * HDIM + sub * 8);
    float s = 0.f;
#pragma unroll
    for (int i = 0; i < 8; ++i) s += bf2f(av[i]) * bf2f(bv[i]);

    s += __shfl_xor(s, 8, 16);
    s += __shfl_xor(s, 4, 16);
    s += __shfl_xor(s, 2, 16);
    s += __shfl_xor(s, 1, 16);

    if (sub == 0 && e < E) out[e] = s + bb[0];
}

extern "C" void kernel_launch(void* const* d_in, const int* in_sizes, int n_in,
                              void* d_out, int out_size, void* d_ws, size_t ws_size,
                              hipStream_t stream)
{
    const float* z  = (const float*)d_in[0];
    const float* w1 = (const float*)d_in[1];
    const float* b1 = (const float*)d_in[2];
    const float* w2 = (const float*)d_in[3];
    const float* b2 = (const float*)d_in[4];
    const float* wb = (const float*)d_in[5];   // (1,128,128) -> 128x128
    const float* bb = (const float*)d_in[6];   // scalar
    const void*  arcs = d_in[7];

    const int N = in_sizes[0] / HDIM;
    const int E = in_sizes[7] / 2;

    char* ws = (char*)d_ws;
    int* flag = (int*)ws;
    unsigned short* g1 = (unsigned short*)(ws + 256);
    unsigned short* h2 = g1 + (size_t)N * HDIM;

    detect_idx64<<<1, 64, 0, stream>>>((const int*)arcs, flag);

    node_phase<<<512, 512, 0, stream>>>(z, w1, b1, w2, b2, wb, g1, h2, N);

    int eblk = (E + 15) / 16;
    edge_phase<<<eblk, 256, 0, stream>>>(g1, h2, arcs, flag, bb, (float*)d_out, E);
}

// Round 3
// 194.609 us; speedup vs baseline: 2.6327x; 2.6327x over previous
//
#include <hip/hip_runtime.h>
#include <hip/hip_bf16.h>

#define HDIM 128

typedef short bf16x8 __attribute__((ext_vector_type(8)));
typedef unsigned short u16x8 __attribute__((ext_vector_type(8)));
typedef float f32x4 __attribute__((ext_vector_type(4)));

__device__ __forceinline__ short f2bf(float f) {
    __hip_bfloat16 h = __float2bfloat16(f);
    union { __hip_bfloat16 h; short s; } c; c.h = h; return c.s;
}
__device__ __forceinline__ float bf2f(unsigned short h) {
    union { unsigned u; float f; } c; c.u = ((unsigned)h) << 16; return c.f;
}
__device__ __forceinline__ bf16x8 pack8(float4 a, float4 b) {
    bf16x8 r;
    r[0] = f2bf(a.x); r[1] = f2bf(a.y); r[2] = f2bf(a.z); r[3] = f2bf(a.w);
    r[4] = f2bf(b.x); r[5] = f2bf(b.y); r[6] = f2bf(b.z); r[7] = f2bf(b.w);
    return r;
}

// ---- weight staging into MFMA B-fragment order (512-thread versions) ----
// Fragment (nt,kt): lane l holds B[k = kt*32 + (l>>4)*8 + i][n = nt*16 + (l&15)],
// stored at wfrag[((nt*4+kt)*64 + l)*8 + i] (bf16). LDS writes are LINEAR b128.
//
// stage_T: B[k][n] = W[n][k]  (for h = z @ W^T) — per-slot 8 contiguous floats.
__device__ __forceinline__ void stage_T(const float* __restrict__ W, short* wfrag, int t) {
#pragma unroll
    for (int s = 0; s < 4; ++s) {
        int S = t + (s << 9);            // 0..2047
        int f = S >> 6, sl = S & 63;     // frag id, lane slot
        int n  = ((f >> 2) << 4) + (sl & 15);
        int k0 = ((f & 3) << 5) + ((sl >> 4) << 3);
        const float* p = W + n * HDIM + k0;
        float4 a = *(const float4*)p;
        float4 b = *(const float4*)(p + 4);
        *(bf16x8*)&wfrag[S << 3] = pack8(a, b);
    }
}
// stage_D: B[k][n] = W[k][n]  (for g1 = h1 @ wb) — per-slot 8 strided floats
// (column gather from global), LDS write stays linear b128: no LDS scatter.
__device__ __forceinline__ void stage_D(const float* __restrict__ W, short* wfrag, int t) {
#pragma unroll
    for (int s = 0; s < 4; ++s) {
        int S = t + (s << 9);
        int f = S >> 6, sl = S & 63;
        int n  = ((f >> 2) << 4) + (sl & 15);
        int k0 = ((f & 3) << 5) + ((sl >> 4) << 3);
        const float* p = W + (size_t)k0 * HDIM + n;
        bf16x8 r;
#pragma unroll
        for (int i = 0; i < 8; ++i) r[i] = f2bf(p[i * HDIM]);
        *(bf16x8*)&wfrag[S << 3] = r;
    }
}

__device__ __forceinline__ void run_gemm8(const short* wfrag, const bf16x8* a, f32x4* acc, int lane) {
#pragma unroll
    for (int kt = 0; kt < 4; ++kt) {
#pragma unroll
        for (int nt = 0; nt < 8; ++nt) {
            bf16x8 b = *(const bf16x8*)&wfrag[((((nt << 2) + kt) << 6) + lane) << 3];
            acc[nt] = __builtin_amdgcn_mfma_f32_16x16x32_bf16(a[kt], b, acc[nt], 0, 0, 0);
        }
    }
}

// ---- phase 1 (persistent): h1=relu(z@w1^T+b1); g1=h1@wb; h2=relu(z@w2^T+b2)
__global__ __launch_bounds__(512, 2)
void node_phase(const float* __restrict__ z,
                const float* __restrict__ w1, const float* __restrict__ b1,
                const float* __restrict__ w2, const float* __restrict__ b2,
                const float* __restrict__ wb,
                unsigned short* __restrict__ g1, unsigned short* __restrict__ h2o,
                int N)
{
    __shared__ short wf1[16384];            // 32 KB each
    __shared__ short wf2[16384];
    __shared__ short wfb[16384];
    __shared__ short rbuf[8 * 16 * HDIM];   // 32 KB: per-wave 16x128 swizzled repack

    const int t = threadIdx.x;
    const int lane = t & 63, wid = t >> 6;
    const int l15 = lane & 15, kgrp = lane >> 4;

    stage_T(w1, wf1, t);
    stage_T(w2, wf2, t);
    stage_D(wb, wfb, t);

    float bias1[8], bias2[8];
#pragma unroll
    for (int nt = 0; nt < 8; ++nt) {
        bias1[nt] = b1[nt * 16 + l15];
        bias2[nt] = b2[nt * 16 + l15];
    }
    __syncthreads();   // only barrier in the kernel

    const int ntiles = (N + 127) >> 7;
    const int wbase = wid * (16 * HDIM);

    float4 cur[8];
    int tile = blockIdx.x;
    if (tile < ntiles) {
        int m = tile * 128 + wid * 16 + l15;
        int mc = m < N ? m : N - 1;
        const float4* zr = (const float4*)(z + (size_t)mc * HDIM);
#pragma unroll
        for (int kt = 0; kt < 4; ++kt) {
            cur[2 * kt]     = zr[kt * 8 + kgrp * 2];
            cur[2 * kt + 1] = zr[kt * 8 + kgrp * 2 + 1];
        }
    }

    for (; tile < ntiles; tile += gridDim.x) {
        // prefetch next tile's z rows (only 16 coalesced stores can sit between
        // these loads and their use next iteration -> no vmcnt drain)
        float4 nxt[8];
        int tnext = tile + gridDim.x;
        if (tnext < ntiles) {
            int m = tnext * 128 + wid * 16 + l15;
            int mc = m < N ? m : N - 1;
            const float4* zr = (const float4*)(z + (size_t)mc * HDIM);
#pragma unroll
            for (int kt = 0; kt < 4; ++kt) {
                nxt[2 * kt]     = zr[kt * 8 + kgrp * 2];
                nxt[2 * kt + 1] = zr[kt * 8 + kgrp * 2 + 1];
            }
        }

        bf16x8 za[4];
#pragma unroll
        for (int kt = 0; kt < 4; ++kt) za[kt] = pack8(cur[2 * kt], cur[2 * kt + 1]);

        const int mwave = tile * 128 + wid * 16;

        // ---- GEMM1: h1 = relu(z @ w1^T + b1) -> rbuf (swizzled) ----
        f32x4 acc[8];
#pragma unroll
        for (int nt = 0; nt < 8; ++nt) {
            float bv = bias1[nt];
            acc[nt] = (f32x4){bv, bv, bv, bv};
        }
        run_gemm8(wf1, za, acc, lane);
#pragma unroll
        for (int nt = 0; nt < 8; ++nt) {
#pragma unroll
            for (int r = 0; r < 4; ++r) {
                float v = acc[nt][r]; v = v > 0.f ? v : 0.f;
                int row = kgrp * 4 + r;
                int col = nt * 16 + l15;
                rbuf[wbase + row * HDIM + (col ^ ((row & 7) << 3))] = f2bf(v);
            }
        }

        // ---- GEMM3: h2 = relu(z @ w2^T + b2)  (rbuf writes settle underneath) ----
        f32x4 acc2[8];
#pragma unroll
        for (int nt = 0; nt < 8; ++nt) {
            float bv = bias2[nt];
            acc2[nt] = (f32x4){bv, bv, bv, bv};
        }
        run_gemm8(wf2, za, acc2, lane);

        // h1 back as A fragments for GEMM2 (same wave, DS is in-order)
        bf16x8 a2[4];
#pragma unroll
        for (int kt = 0; kt < 4; ++kt) {
            int col = kt * 32 + kgrp * 8;
            a2[kt] = *(const bf16x8*)&rbuf[wbase + l15 * HDIM + (col ^ ((l15 & 7) << 3))];
        }
        asm volatile("s_waitcnt lgkmcnt(0)" ::: "memory");

        // ---- h2: repack through rbuf -> coalesced 16B stores ----
#pragma unroll
        for (int nt = 0; nt < 8; ++nt) {
#pragma unroll
            for (int r = 0; r < 4; ++r) {
                float v = acc2[nt][r]; v = v > 0.f ? v : 0.f;
                int row = kgrp * 4 + r;
                int col = nt * 16 + l15;
                rbuf[wbase + row * HDIM + (col ^ ((row & 7) << 3))] = f2bf(v);
            }
        }
#pragma unroll
        for (int j = 0; j < 4; ++j) {
            int row = (lane >> 4) + 4 * j;
            int c0  = (lane & 15) * 8;
            u16x8 vv = *(const u16x8*)&rbuf[wbase + row * HDIM + (c0 ^ ((row & 7) << 3))];
            int m = mwave + row;
            if (m < N) *(u16x8*)&h2o[(size_t)m * HDIM + c0] = vv;
        }

        // ---- GEMM2: g1 = h1 @ wb -> repack -> coalesced stores ----
        f32x4 accg[8];
#pragma unroll
        for (int nt = 0; nt < 8; ++nt) accg[nt] = (f32x4){0.f, 0.f, 0.f, 0.f};
        run_gemm8(wfb, a2, accg, lane);
        asm volatile("s_waitcnt lgkmcnt(0)" ::: "memory");
#pragma unroll
        for (int nt = 0; nt < 8; ++nt) {
#pragma unroll
            for (int r = 0; r < 4; ++r) {
                int row = kgrp * 4 + r;
                int col = nt * 16 + l15;
                rbuf[wbase + row * HDIM + (col ^ ((row & 7) << 3))] = f2bf(accg[nt][r]);
            }
        }
#pragma unroll
        for (int j = 0; j < 4; ++j) {
            int row = (lane >> 4) + 4 * j;
            int c0  = (lane & 15) * 8;
            u16x8 vv = *(const u16x8*)&rbuf[wbase + row * HDIM + (c0 ^ ((row & 7) << 3))];
            int m = mwave + row;
            if (m < N) *(u16x8*)&g1[(size_t)m * HDIM + c0] = vv;
        }

        // rotate double buffer
#pragma unroll
        for (int q = 0; q < 8; ++q) cur[q] = nxt[q];
    }
}

// ---- index dtype detection: int64 arcs have zero high words -------------
__global__ void detect_idx64(const int* __restrict__ arcs, int* __restrict__ flag)
{
    if (threadIdx.x == 0) {
        int is64 = 1;
        for (int j = 0; j < 64; ++j)
            if (arcs[2 * j + 1] != 0) { is64 = 0; break; }
        *flag = is64;
    }
}

// ---- phase 2: score[e] = dot(g1[u], h2[v]) + bb -------------------------
__global__ __launch_bounds__(256, 8)
void edge_phase(const unsigned short* __restrict__ g1,
                const unsigned short* __restrict__ h2,
                const void* __restrict__ arcs,
                const int* __restrict__ flag,
                const float* __restrict__ bb,
                float* __restrict__ out, int E)
{
    const int t = threadIdx.x;
    const int sub = t & 15;
    const int e = blockIdx.x * 16 + (t >> 4);
    const int ec = e < E ? e : (E - 1);

    long long u, v;
    if (*flag) {
        const long long* a = (const long long*)arcs;
        u = a[2 * (size_t)ec]; v = a[2 * (size_t)ec + 1];
    } else {
        const int* a = (const int*)arcs;
        u = a[2 * (size_t)ec]; v = a[2 * (size_t)ec + 1];
    }

    u16x8 av = *(const u16x8*)(g1 + (size_t)u * HDIM + sub * 8);
    u16x8 bv = *(const u16x8*)(h2 + (size_t)v * HDIM + sub * 8);
    float s = 0.f;
#pragma unroll
    for (int i = 0; i < 8; ++i) s += bf2f(av[i]) * bf2f(bv[i]);

    s += __shfl_xor(s, 8, 16);
    s += __shfl_xor(s, 4, 16);
    s += __shfl_xor(s, 2, 16);
    s += __shfl_xor(s, 1, 16);

    if (sub == 0 && e < E) out[e] = s + bb[0];
}

extern "C" void kernel_launch(void* const* d_in, const int* in_sizes, int n_in,
                              void* d_out, int out_size, void* d_ws, size_t ws_size,
                              hipStream_t stream)
{
    const float* z  = (const float*)d_in[0];
    const float* w1 = (const float*)d_in[1];
    const float* b1 = (const float*)d_in[2];
    const float* w2 = (const float*)d_in[3];
    const float* b2 = (const float*)d_in[4];
    const float* wb = (const float*)d_in[5];   // (1,128,128) -> 128x128
    const float* bb = (const float*)d_in[6];   // scalar
    const void*  arcs = d_in[7];

    const int N = in_sizes[0] / HDIM;
    const int E = in_sizes[7] / 2;

    char* ws = (char*)d_ws;
    int* flag = (int*)ws;
    unsigned short* g1 = (unsigned short*)(ws + 256);
    unsigned short* h2 = g1 + (size_t)N * HDIM;

    detect_idx64<<<1, 64, 0, stream>>>((const int*)arcs, flag);

    node_phase<<<256, 512, 0, stream>>>(z, w1, b1, w2, b2, wb, g1, h2, N);

    int eblk = (E + 15) / 16;
    edge_phase<<<eblk, 256, 0, stream>>>(g1, h2, arcs, flag, bb, (float*)d_out, E);
}